// Round 7
// baseline (477.054 us; speedup 1.0000x reference)
//
#include <hip/hip_runtime.h>
#include <hip/hip_bf16.h>
#include <math.h>

// Problem constants
#define BB 4
#define SS 2048
#define DD 1024
#define HH 16
#define HD 64

#define NEG_BIG (-1e30f)  // finite "-inf": exp(NEG_BIG - m) == 0

// Verified facts (rounds 0-12):
//  - fp32 inputs, fp32 output; MFMA C/D layout col=lane&15,row=quad*4+reg
//  - ws_size >= 2*NE shorts (33.5 MB)
//  - r7 (cvt_pk, ones-MFMA denom, setprio): 575->504
//  - r9 (2-phase dbuf GEMM + 128-row attn): REGRESSED => don't source-pipeline
//    2-barrier loops (m99/m100/m131-141)
//  - r10 (bf16 weights, all-gll GEMMs): 475us
//  - r11 (3 coupled LDS-layout changes): FAILED; r12 isolated the K/V swizzle:
//    conflicts 9.73M->1.08M, attn 195->186, total 464. Swizzle side verified.
// Round 13 (single structural change):
//  - Q/K/V projections FUSED into one launch, grid (8,64,3) = 1536 blocks
//    (vs 3 serial 512-block kernels at 2 blocks/CU). Activations read
//    directly as fp32 + reg-staged (r8: inline cvt == preconvert cost);
//    weights bf16 via gll. Kills both 16MB act-conv kernels + 48MB traffic.
//  - attn r12-verbatim; out-proj r10-verbatim; weight convs unchanged.

typedef short v8s __attribute__((ext_vector_type(8)));
typedef float v4f __attribute__((ext_vector_type(4)));

__device__ inline unsigned cvt_pk_bf16(float lo, float hi) {
    unsigned r;
    asm("v_cvt_pk_bf16_f32 %0, %1, %2" : "=v"(r) : "v"(lo), "v"(hi));
    return r;
}

__device__ inline short f2bf(float f) {
    return (short)cvt_pk_bf16(f, f);
}

__device__ inline v4f v4f_zero() {
    v4f z;
    z[0] = 0.f; z[1] = 0.f; z[2] = 0.f; z[3] = 0.f;
    return z;
}

__device__ inline v8s cvt8(v4f a, v4f b) {
    union { unsigned u[4]; v8s s; } x;
    x.u[0] = cvt_pk_bf16(a[0], a[1]);
    x.u[1] = cvt_pk_bf16(a[2], a[3]);
    x.u[2] = cvt_pk_bf16(b[0], b[1]);
    x.u[3] = cvt_pk_bf16(b[2], b[3]);
    return x.s;
}

__device__ inline v8s load8f(const float* p) {
    return cvt8(*(const v4f*)p, *(const v4f*)(p + 4));
}

// Async global->LDS, 16B/lane. LDS dest wave-uniform base; lane i -> base+16i.
__device__ inline void gll16(const void* g, void* l) {
    __builtin_amdgcn_global_load_lds(
        (const __attribute__((address_space(1))) unsigned*)g,
        (__attribute__((address_space(3))) unsigned*)l, 16, 0, 0);
}

// ---------------------------------------------------------------------------
// fp32 -> bf16 elementwise (vectorized, grid-stride). n8 = elems/8.
// ---------------------------------------------------------------------------
__global__ __launch_bounds__(256) void conv_bf16_kernel(
    const float* __restrict__ in, short* __restrict__ out, int n8) {
    int i = blockIdx.x * 256 + threadIdx.x;
    const int stride = gridDim.x * 256;
    for (; i < n8; i += stride) {
        *((v8s*)out + i) = load8f(in + (size_t)i * 8);
    }
}

// ---------------------------------------------------------------------------
// FUSED Q/K/V projections. Grid (8,64,3); z selects {act, W, bias, C, layout}.
// C[M,N] = act[M,K] * W[N,K]^T + bias. act fp32 reg-staged; W bf16 via gll.
// z=0: Q -> [B,H,S,HD]; z=1: K -> [B,H,S,HD]; z=2: V -> [B,H,HD,S] (V^T).
// Tiles: BM=BN=128, BK=32; 4 waves (2x2), 64x64/wave; m97 2-barrier loop.
// ---------------------------------------------------------------------------
__global__ __launch_bounds__(256) void fused_qkv_kernel(
    const float* __restrict__ actq, const float* __restrict__ actk,
    const float* __restrict__ actv, const short* __restrict__ wqp,
    const short* __restrict__ wkp, const short* __restrict__ wvp,
    const float* __restrict__ bqp, const float* __restrict__ bkp,
    const float* __restrict__ bvp, short* __restrict__ cq,
    short* __restrict__ ck, short* __restrict__ cv) {
    __shared__ short sA[128 * 32];
    __shared__ short sB[128 * 32];

    const int tid = threadIdx.x;
    const int lane = tid & 63;
    const int wave = tid >> 6;
    const int quad = lane >> 4;
    const int l16 = lane & 15;
    const int wm = wave >> 1;
    const int wn = wave & 1;
    const int z = blockIdx.z;

    const float* act = (z == 0) ? actq : (z == 1) ? actk : actv;
    const short* W = (z == 0) ? wqp : (z == 1) ? wkp : wvp;
    const float* bias = (z == 0) ? bqp : (z == 1) ? bkp : bvp;
    short* Cv = (z == 0) ? cq : (z == 1) ? ck : cv;

    // XCD swizzle: group the 8 n-tiles of one m-panel on one XCD
    int b = blockIdx.x + (blockIdx.y << 3);
    int l = ((b & 7) << 6) + (b >> 3);
    const int bx = l & 7;
    const int by = l >> 3;
    const int m0 = by * 128;
    const int n0 = bx * 128;

    // B (weight bf16) gll addressing
    const int grow = (wave << 5) + (lane >> 2);
    const int gcol = (lane & 3) << 3;
    const int ldoff = wave << 10;
    const size_t gaB0 = (size_t)(n0 + grow) * 1024 + gcol;
    const size_t gaB1 = gaB0 + (size_t)16 * 1024;

    // A (activation fp32) reg-stage addressing
    const int idx0 = tid << 3, idx1 = (256 + tid) << 3;
    const float* Asrc0 = act + (size_t)(m0 + (idx0 >> 5)) * 1024 + (idx0 & 31);
    const float* Asrc1 = act + (size_t)(m0 + (idx1 >> 5)) * 1024 + (idx1 & 31);

    v4f acc[4][4];
#pragma unroll
    for (int i = 0; i < 4; i++)
#pragma unroll
        for (int j = 0; j < 4; j++) acc[i][j] = v4f_zero();

    for (int k0 = 0; k0 < 1024; k0 += 32) {
        __syncthreads();
        gll16(W + gaB0 + k0, sB + ldoff);
        gll16(W + gaB1 + k0, sB + ldoff + 512);
        *(v8s*)&sA[idx0] = load8f(Asrc0 + k0);
        *(v8s*)&sA[idx1] = load8f(Asrc1 + k0);
        __syncthreads();

        v8s af[4], bfr[4];
#pragma unroll
        for (int i = 0; i < 4; i++)
            af[i] = *(const v8s*)&sA[(wm * 64 + i * 16 + l16) * 32 + quad * 8];
#pragma unroll
        for (int j = 0; j < 4; j++)
            bfr[j] = *(const v8s*)&sB[(wn * 64 + j * 16 + l16) * 32 + quad * 8];
#pragma unroll
        for (int i = 0; i < 4; i++)
#pragma unroll
            for (int j = 0; j < 4; j++)
                acc[i][j] = __builtin_amdgcn_mfma_f32_16x16x32_bf16(
                    af[i], bfr[j], acc[i][j], 0, 0, 0);
    }

    // Epilogue: C/D layout col = lane&15, row = quad*4 + reg (HW-verified r6)
#pragma unroll
    for (int i = 0; i < 4; i++) {
#pragma unroll
        for (int j = 0; j < 4; j++) {
#pragma unroll
            for (int r = 0; r < 4; r++) {
                int ml = wm * 64 + i * 16 + quad * 4 + r;
                int nl = wn * 64 + j * 16 + l16;
                int m = m0 + ml;
                int n = n0 + nl;
                float v = acc[i][j][r] + bias[n];
                int bb = m >> 11, s = m & 2047, h = n >> 6, d = n & 63;
                if (z < 2) {
                    // [B,H,S,HD]
                    Cv[(((size_t)(bb * HH + h) * SS + s) << 6) + d] = f2bf(v);
                } else {
                    // V^T: [B,H,HD,S]
                    Cv[((size_t)(bb * HH + h) * HD + d) * SS + s] = f2bf(v);
                }
            }
        }
    }
}

// ---------------------------------------------------------------------------
// Out-projection GEMM (r10-verbatim MODE 3): A = O bf16 ws [B,H,S,HD] remap
// via gll; B = Wo bf16 gll; C fp32 row-major. Grid (8,64).
// ---------------------------------------------------------------------------
__global__ __launch_bounds__(256) void gemm_out_kernel(
    const void* __restrict__ Av, const void* __restrict__ Bv,
    const float* __restrict__ bias, void* __restrict__ Cv) {
    __shared__ short sA[128 * 32];
    __shared__ short sB[128 * 32];

    const int tid = threadIdx.x;
    const int lane = tid & 63;
    const int wave = tid >> 6;
    const int quad = lane >> 4;
    const int l16 = lane & 15;
    const int wm = wave >> 1;
    const int wn = wave & 1;

    int b = blockIdx.x + (blockIdx.y << 3);
    int l = ((b & 7) << 6) + (b >> 3);
    const int bx = l & 7;
    const int by = l >> 3;
    const int m0 = by * 128;
    const int n0 = bx * 128;

    const int grow = (wave << 5) + (lane >> 2);
    const int gcol = (lane & 3) << 3;
    const int ldoff = wave << 10;

    const short* As = (const short*)Av;
    int ma = m0 + grow, mb = m0 + grow + 16;
    const size_t gaA0 = ((size_t)((ma >> 11) * HH) * SS + (ma & 2047)) * HD;
    const size_t gaA1 = ((size_t)((mb >> 11) * HH) * SS + (mb & 2047)) * HD;

    const short* Bs = (const short*)Bv;
    const size_t gaB0 = (size_t)(n0 + grow) * 1024 + gcol;
    const size_t gaB1 = gaB0 + (size_t)16 * 1024;

    v4f acc[4][4];
#pragma unroll
    for (int i = 0; i < 4; i++)
#pragma unroll
        for (int j = 0; j < 4; j++) acc[i][j] = v4f_zero();

    for (int k0 = 0; k0 < 1024; k0 += 32) {
        __syncthreads();
        size_t hoff = (size_t)(k0 >> 6) * (SS * HD) + (k0 & 63) + gcol;
        gll16(As + gaA0 + hoff, sA + ldoff);
        gll16(As + gaA1 + hoff, sA + ldoff + 512);
        gll16(Bs + gaB0 + k0, sB + ldoff);
        gll16(Bs + gaB1 + k0, sB + ldoff + 512);
        __syncthreads();

        v8s af[4], bfr[4];
#pragma unroll
        for (int i = 0; i < 4; i++)
            af[i] = *(const v8s*)&sA[(wm * 64 + i * 16 + l16) * 32 + quad * 8];
#pragma unroll
        for (int j = 0; j < 4; j++)
            bfr[j] = *(const v8s*)&sB[(wn * 64 + j * 16 + l16) * 32 + quad * 8];
#pragma unroll
        for (int i = 0; i < 4; i++)
#pragma unroll
            for (int j = 0; j < 4; j++)
                acc[i][j] = __builtin_amdgcn_mfma_f32_16x16x32_bf16(
                    af[i], bfr[j], acc[i][j], 0, 0, 0);
    }

#pragma unroll
    for (int i = 0; i < 4; i++) {
#pragma unroll
        for (int j = 0; j < 4; j++) {
#pragma unroll
            for (int r = 0; r < 4; r++) {
                int ml = wm * 64 + i * 16 + quad * 4 + r;
                int nl = wn * 64 + j * 16 + l16;
                int m = m0 + ml;
                int n = n0 + nl;
                ((float*)Cv)[(size_t)m * 1024 + n] = acc[i][j][r] + bias[n];
            }
        }
    }
}

// ---------------------------------------------------------------------------
// Flash attention (causal, MFMA). Grid: (S/64, B*H). 256 thr = 4 waves.
// r12-verbatim (186us): sK/sV T2 XOR swizzle (stride 64, cs = c^((r&7)<<3));
// sP LDR=72 C-layout; ones-MFMA denominator; no mid-barrier; setprio;
// reversed qt order.
// ---------------------------------------------------------------------------
__global__ __launch_bounds__(256) void attn_kernel(
    short* __restrict__ QO, const short* __restrict__ Kt,
    const short* __restrict__ Vt) {
    constexpr int LDR = 64 + 8;           // sP stride
    __shared__ short sK[64 * 64];
    __shared__ short sV[64 * 64];
    __shared__ short sP[4][16 * LDR];

    const int tid = threadIdx.x;
    const int lane = tid & 63;
    const int wave = tid >> 6;
    const int quad = lane >> 4;
    const int l16 = lane & 15;
    const int qt = (int)gridDim.x - 1 - (int)blockIdx.x;
    const int bh = blockIdx.y;

    short* Qh = QO + (size_t)bh * SS * HD;
    const short* Kh = Kt + (size_t)bh * SS * HD;
    const short* Vh = Vt + (size_t)bh * HD * SS;

    const int qrow = qt * 64 + wave * 16 + l16;
    v8s qf[2];
    qf[0] = *(const v8s*)&Qh[(size_t)qrow * HD + quad * 8];
    qf[1] = *(const v8s*)&Qh[(size_t)qrow * HD + 32 + quad * 8];

    v8s onesb;
#pragma unroll
    for (int i = 0; i < 8; i++) onesb[i] = (short)0x3F80;  // bf16 1.0

    v4f o[4];
#pragma unroll
    for (int j = 0; j < 4; j++) o[j] = v4f_zero();
    v4f oSum = v4f_zero();
    float mOld[4];
#pragma unroll
    for (int r = 0; r < 4; r++) mOld[r] = NEG_BIG;

    const int qg_base = qt * 64 + wave * 16 + quad * 4;

    const int rc0 = (quad * 8) ^ ((l16 & 7) << 3);
    const int rc1 = (32 + quad * 8) ^ ((l16 & 7) << 3);

    for (int kt = 0; kt <= qt; kt++) {
        __syncthreads();
#pragma unroll
        for (int p = 0; p < 2; p++) {
            int idx = (p * 256 + tid) * 8;
            int r = idx >> 6;
            int c = idx & 63;
            int cs = c ^ ((r & 7) << 3);  // T2 XOR swizzle
            *(v8s*)&sK[r * 64 + cs] =
                *(const v8s*)&Kh[(size_t)(kt * 64 + r) * HD + c];
            *(v8s*)&sV[r * 64 + cs] =
                *(const v8s*)&Vh[(size_t)r * SS + kt * 64 + c];
        }
        __syncthreads();

        __builtin_amdgcn_s_setprio(1);
        v4f sc[4];
#pragma unroll
        for (int j = 0; j < 4; j++) {
            v8s b0 = *(const v8s*)&sK[(j * 16 + l16) * 64 + rc0];
            v8s b1 = *(const v8s*)&sK[(j * 16 + l16) * 64 + rc1];
            v4f t = __builtin_amdgcn_mfma_f32_16x16x32_bf16(qf[0], b0,
                                                            v4f_zero(), 0, 0, 0);
            sc[j] = __builtin_amdgcn_mfma_f32_16x16x32_bf16(qf[1], b1, t, 0, 0, 0);
        }
        __builtin_amdgcn_s_setprio(0);

        float x[4][4];
        const bool diag = (kt == qt);
#pragma unroll
        for (int j = 0; j < 4; j++) {
#pragma unroll
            for (int r = 0; r < 4; r++) {
                float v = sc[j][r] * 0.125f;
                if (diag) {
                    int kg = kt * 64 + j * 16 + l16;
                    int qg = qg_base + r;
                    if (kg > qg) v = NEG_BIG;
                }
                x[j][r] = v;
            }
        }

        float mNew[4], alpha[4];
#pragma unroll
        for (int r = 0; r < 4; r++) {
            float t = fmaxf(fmaxf(x[0][r], x[1][r]), fmaxf(x[2][r], x[3][r]));
#pragma unroll
            for (int off = 8; off >= 1; off >>= 1) t = fmaxf(t, __shfl_xor(t, off));
            mNew[r] = fmaxf(mOld[r], t);
            alpha[r] = __expf(mOld[r] - mNew[r]);
            mOld[r] = mNew[r];
        }

        short* Pw = sP[wave];
#pragma unroll
        for (int j = 0; j < 4; j++)
#pragma unroll
            for (int r = 0; r < 4; r++) {
                float p = __expf(x[j][r] - mNew[r]);
                Pw[(quad * 4 + r) * LDR + j * 16 + l16] = f2bf(p);
            }
#pragma unroll
        for (int j = 0; j < 4; j++)
#pragma unroll
            for (int r = 0; r < 4; r++) o[j][r] *= alpha[r];
#pragma unroll
        for (int r = 0; r < 4; r++) oSum[r] *= alpha[r];

        v8s pa0 = *(const v8s*)&Pw[l16 * LDR + quad * 8];
        v8s pa1 = *(const v8s*)&Pw[l16 * LDR + 32 + quad * 8];
        __builtin_amdgcn_s_setprio(1);
#pragma unroll
        for (int j = 0; j < 4; j++) {
            v8s v0 = *(const v8s*)&sV[(j * 16 + l16) * 64 + rc0];
            v8s v1 = *(const v8s*)&sV[(j * 16 + l16) * 64 + rc1];
            o[j] = __builtin_amdgcn_mfma_f32_16x16x32_bf16(pa0, v0, o[j], 0, 0, 0);
            o[j] = __builtin_amdgcn_mfma_f32_16x16x32_bf16(pa1, v1, o[j], 0, 0, 0);
        }
        oSum = __builtin_amdgcn_mfma_f32_16x16x32_bf16(pa0, onesb, oSum, 0, 0, 0);
        oSum = __builtin_amdgcn_mfma_f32_16x16x32_bf16(pa1, onesb, oSum, 0, 0, 0);
        __builtin_amdgcn_s_setprio(0);
    }

#pragma unroll
    for (int r = 0; r < 4; r++) {
        float inv = 1.f / oSum[r];
        int s = qg_base + r;
#pragma unroll
        for (int j = 0; j < 4; j++) {
            float v = o[j][r] * inv;
            Qh[(size_t)s * HD + j * 16 + l16] = f2bf(v);
        }
    }
}

// ---------------------------------------------------------------------------
extern "C" void kernel_launch(void* const* d_in, const int* in_sizes, int n_in,
                              void* d_out, int out_size, void* d_ws, size_t ws_size,
                              hipStream_t stream) {
    const float* query = (const float*)d_in[0];
    const float* key_ = (const float*)d_in[1];
    const float* value = (const float*)d_in[2];
    const float* Wq = (const float*)d_in[3];
    const float* bq = (const float*)d_in[4];
    const float* Wk = (const float*)d_in[5];
    const float* bk = (const float*)d_in[6];
    const float* Wv = (const float*)d_in[7];
    const float* bv = (const float*)d_in[8];
    const float* Wo = (const float*)d_in[9];
    const float* bo = (const float*)d_in[10];
    float* out = (float*)d_out;

    const size_t NE = (size_t)BB * SS * DD;   // 8388608
    const size_t WE = (size_t)DD * DD;        // 1048576 (one weight matrix)

    // Regions (shorts): DO0=d_out[0:NE], DO1=d_out[NE:2NE],
    //                   WS0=ws[0:NE],    WS1=ws[NE:2NE].
    short* wqb = (short*)d_out;            // DO0[0:WE]      [conv .. QKVproj]
    short* wkb = (short*)d_out + WE;       // DO0[WE:2WE]    [conv .. QKVproj]
    short* wvb = (short*)d_out + 2 * WE;   // DO0[2WE:3WE]   [conv .. QKVproj]
    short* qw  = (short*)d_ws;             // WS0            [QKVproj .. outproj]
    short* kw  = (short*)d_ws + NE;        // WS1            [QKVproj .. attn]
    short* vw  = (short*)d_out + NE;       // DO1            [QKVproj .. attn]
    short* wob = (short*)d_ws + NE;        // WS1[0:WE]      [after attn .. outproj]

    dim3 blk(256);
    const int n8w = (int)(WE / 8);

    // 1) Wq,Wk,Wv -> bf16 in DO0 head (6MB; disjoint from DO1=vw)
    conv_bf16_kernel<<<dim3(512), blk, 0, stream>>>(Wq, wqb, n8w);
    conv_bf16_kernel<<<dim3(512), blk, 0, stream>>>(Wk, wkb, n8w);
    conv_bf16_kernel<<<dim3(512), blk, 0, stream>>>(Wv, wvb, n8w);
    // 2) fused Q/K/V projections: reads fp32 acts + DO0 weights;
    //    writes qw(WS0), kw(WS1), vw(DO1)
    fused_qkv_kernel<<<dim3(8, 64, 3), blk, 0, stream>>>(
        query, key_, value, wqb, wkb, wvb, bq, bk, bv, qw, kw, vw);
    // 3) attention: reads WS0,WS1,DO1; O overwrites WS0
    attn_kernel<<<dim3(SS / 64, BB * HH), blk, 0, stream>>>(qw, kw, vw);
    // 4) Wo -> WS1 head (kw dead after attn)
    conv_bf16_kernel<<<dim3(512), blk, 0, stream>>>(Wo, wob, n8w);
    // 5) out proj: reads WS0 (O, remap) + WS1 (Wo); writes d_out fp32
    //    (overwrites DO0/DO1 — weights + vw are dead)
    gemm_out_kernel<<<dim3(8, 64), blk, 0, stream>>>(qw, wob, bo, out);
}

// Round 8
// 447.780 us; speedup vs baseline: 1.0654x; 1.0654x over previous
//
#include <hip/hip_runtime.h>
#include <hip/hip_bf16.h>
#include <math.h>

// Problem constants
#define BB 4
#define SS 2048
#define DD 1024
#define HH 16
#define HD 64

#define NEG_BIG (-1e30f)  // finite "-inf": exp(NEG_BIG - m) == 0

// Verified facts (rounds 0-13):
//  - fp32 inputs, fp32 output; MFMA C/D layout col=lane&15,row=quad*4+reg
//  - ws_size >= 2*NE shorts (33.5 MB)
//  - r7 (cvt_pk, ones-MFMA denom, setprio): 575->504
//  - r9/r13 (GEMM dbuf-pipeline / QKV-fuse with fp32 staging): both REGRESSED
//    => keep the all-gll 2-barrier m97 structure; don't add overlap.
//  - r10 (bf16 weights, all-gll GEMMs): 475us
//  - r12 (T2 XOR swizzle on attn sK/sV): conflicts 9.73M->1.08M, 464us BEST.
// Round 14 (single variable, GEMM only):
//  - BK 32->64: halves K-loop iterations => halves the per-iteration
//    vmcnt+lgkm barrier drains (the cost at 2 blocks/CU). 32 MFMA/stage.
//  - 128x64 tile (128B rows) would be 16-way conflicted on ds_read_b128;
//    fixed via rule-21: linear gll dest + PRE-SWIZZLED global source col
//    8*((lane&7)^(lane>>3)) + swizzled read col ^((l16&7)<<3) — the same
//    involution HW-verified in r12's sK/sV. MODE 1 reg-staged B writes the
//    swizzled LDS address directly.
//  - attn r12-verbatim; launch plan r12-verbatim.

typedef short v8s __attribute__((ext_vector_type(8)));
typedef float v4f __attribute__((ext_vector_type(4)));

__device__ inline unsigned cvt_pk_bf16(float lo, float hi) {
    unsigned r;
    asm("v_cvt_pk_bf16_f32 %0, %1, %2" : "=v"(r) : "v"(lo), "v"(hi));
    return r;
}

__device__ inline short f2bf(float f) {
    return (short)cvt_pk_bf16(f, f);
}

__device__ inline v4f v4f_zero() {
    v4f z;
    z[0] = 0.f; z[1] = 0.f; z[2] = 0.f; z[3] = 0.f;
    return z;
}

__device__ inline v8s cvt8(v4f a, v4f b) {
    union { unsigned u[4]; v8s s; } x;
    x.u[0] = cvt_pk_bf16(a[0], a[1]);
    x.u[1] = cvt_pk_bf16(a[2], a[3]);
    x.u[2] = cvt_pk_bf16(b[0], b[1]);
    x.u[3] = cvt_pk_bf16(b[2], b[3]);
    return x.s;
}

__device__ inline v8s load8f(const float* p) {
    return cvt8(*(const v4f*)p, *(const v4f*)(p + 4));
}

// Async global->LDS, 16B/lane. LDS dest wave-uniform base; lane i -> base+16i.
__device__ inline void gll16(const void* g, void* l) {
    __builtin_amdgcn_global_load_lds(
        (const __attribute__((address_space(1))) unsigned*)g,
        (__attribute__((address_space(3))) unsigned*)l, 16, 0, 0);
}

// ---------------------------------------------------------------------------
// fp32 -> bf16 elementwise (vectorized, grid-stride). n8 = elems/8.
// ---------------------------------------------------------------------------
__global__ __launch_bounds__(256) void conv_bf16_kernel(
    const float* __restrict__ in, short* __restrict__ out, int n8) {
    int i = blockIdx.x * 256 + threadIdx.x;
    const int stride = gridDim.x * 256;
    for (; i < n8; i += stride) {
        *((v8s*)out + i) = load8f(in + (size_t)i * 8);
    }
}

// ---------------------------------------------------------------------------
// NT GEMM: C[M,N] = A[M,K] * B[N,K]^T + bias, fp32 accum, bf16 MFMA. K=1024.
// BK=64, single-buffer, 2 barriers per K-step, 16 K-steps (vs 32 at BK=32).
// LDS tiles 128x64 bf16, XOR-swizzled (see header). A/B via gll with
// pre-swizzled global source col; MODE 1 B (fp32 value) reg-staged to the
// swizzled LDS address.
// MODE 0: A act bf16 gll [8192,1024]; B wt bf16 gll; C bf16 [B,H,S,HD]. (8,64)
// MODE 1: A wt bf16 gll [1024,1024]; B value fp32 reg-staged [8192,1024];
//         C bf16 [B,H,HD,S]. grid (64,8).
// MODE 3: A O-bf16 ws remap gll; B wt bf16 gll; C fp32 row-major. (8,64)
// Tiles: BM=BN=128; 256 thr = 4 waves (2x2), 64x64 per wave.
// ---------------------------------------------------------------------------
template <int MODE>
__global__ __launch_bounds__(256) void gemm_kernel(
    const void* __restrict__ Av, const void* __restrict__ Bv,
    const float* __restrict__ bias, void* __restrict__ Cv) {
    __shared__ short sA[128 * 64];
    __shared__ short sB[128 * 64];

    const int tid = threadIdx.x;
    const int lane = tid & 63;
    const int wave = tid >> 6;
    const int quad = lane >> 4;
    const int l16 = lane & 15;
    const int wm = wave >> 1;
    const int wn = wave & 1;

    int bx, by;
    if (MODE != 1) {
        // XCD swizzle: group the 8 n-tiles of one m-panel on one XCD
        int b = blockIdx.x + (blockIdx.y << 3);
        int l = ((b & 7) << 6) + (b >> 3);
        bx = l & 7;
        by = l >> 3;
    } else {
        bx = blockIdx.x;
        by = blockIdx.y;
    }
    const int m0 = by * 128;
    const int n0 = bx * 128;

    // gll staging (BK=64): wave w stages rows w*32+g*8+(lane>>3), g=0..3.
    // Global source col is PRE-SWIZZLED so linear LDS holds the swizzled
    // layout: elem(row,colG) lives at LDS col colG ^ ((row&7)<<3);
    // row&7 == lane>>3 for gll lanes.
    const int grow0 = (wave << 5) + (lane >> 3);
    const int gcs = ((lane & 7) ^ (lane >> 3)) << 3;  // pre-swizzled col
    const int ldoff = wave << 11;                      // wave*2048 shorts

    const short* As = (const short*)Av;
    const short* Bs = (const short*)Bv;
    const float* Bf = (const float*)Bv;

    size_t gaA[4], gaB[4];
#pragma unroll
    for (int g = 0; g < 4; g++) {
        int row = grow0 + g * 8;
        if (MODE == 3) {
            int ma = m0 + row;
            gaA[g] = ((size_t)((ma >> 11) * HH) * SS + (ma & 2047)) * HD + gcs;
        } else {
            gaA[g] = (size_t)(m0 + row) * 1024 + gcs;
        }
        if (MODE != 1) gaB[g] = (size_t)(n0 + row) * 1024 + gcs;
    }

    // MODE 1 B reg-stage: 4 x (load8f + swizzled ds_write) per K-step
    const float* Bsrc[4];
    int bidx[4];
#pragma unroll
    for (int p = 0; p < 4; p++) {
        int idx = ((p << 8) + tid) << 3;
        int row = idx >> 6;
        int col = idx & 63;
        Bsrc[p] = Bf + (size_t)(n0 + row) * 1024 + col;
        bidx[p] = (row << 6) + (col ^ ((row & 7) << 3));
    }

    v4f acc[4][4];
#pragma unroll
    for (int i = 0; i < 4; i++)
#pragma unroll
        for (int j = 0; j < 4; j++) acc[i][j] = v4f_zero();

    for (int k0 = 0; k0 < 1024; k0 += 64) {
        __syncthreads();
        if (MODE == 3) {
            size_t hoff = (size_t)(k0 >> 6) * (SS * HD);
#pragma unroll
            for (int g = 0; g < 4; g++)
                gll16(As + gaA[g] + hoff, sA + ldoff + g * 512);
        } else {
#pragma unroll
            for (int g = 0; g < 4; g++)
                gll16(As + gaA[g] + k0, sA + ldoff + g * 512);
        }
        if (MODE == 1) {
#pragma unroll
            for (int p = 0; p < 4; p++)
                *(v8s*)&sB[bidx[p]] = load8f(Bsrc[p] + k0);
        } else {
#pragma unroll
            for (int g = 0; g < 4; g++)
                gll16(Bs + gaB[g] + k0, sB + ldoff + g * 512);
        }
        __syncthreads();

#pragma unroll
        for (int kk = 0; kk < 2; kk++) {
            const int csk = (kk * 32 + quad * 8) ^ ((l16 & 7) << 3);
            v8s af[4], bfr[4];
#pragma unroll
            for (int i = 0; i < 4; i++)
                af[i] = *(const v8s*)&sA[(wm * 64 + i * 16 + l16) * 64 + csk];
#pragma unroll
            for (int j = 0; j < 4; j++)
                bfr[j] = *(const v8s*)&sB[(wn * 64 + j * 16 + l16) * 64 + csk];
#pragma unroll
            for (int i = 0; i < 4; i++)
#pragma unroll
                for (int j = 0; j < 4; j++)
                    acc[i][j] = __builtin_amdgcn_mfma_f32_16x16x32_bf16(
                        af[i], bfr[j], acc[i][j], 0, 0, 0);
        }
    }

    // Epilogue: C/D layout col = lane&15, row = quad*4 + reg (HW-verified r6)
#pragma unroll
    for (int i = 0; i < 4; i++) {
#pragma unroll
        for (int j = 0; j < 4; j++) {
#pragma unroll
            for (int r = 0; r < 4; r++) {
                int ml = wm * 64 + i * 16 + quad * 4 + r;
                int nl = wn * 64 + j * 16 + l16;
                int m = m0 + ml;
                int n = n0 + nl;
                float v = acc[i][j][r];
                if (MODE == 0) {
                    v += bias[n];
                    int b = m >> 11, s = m & 2047, h = n >> 6, d = n & 63;
                    ((short*)Cv)[(((size_t)(b * HH + h) * SS + s) << 6) + d] =
                        f2bf(v);
                } else if (MODE == 1) {
                    v += bias[m];
                    int h = m >> 6, d = m & 63, b = n >> 11, s = n & 2047;
                    ((short*)Cv)[((size_t)(b * HH + h) * HD + d) * SS + s] =
                        f2bf(v);
                } else {
                    v += bias[n];
                    ((float*)Cv)[(size_t)m * 1024 + n] = v;
                }
            }
        }
    }
}

// ---------------------------------------------------------------------------
// Flash attention (causal, MFMA). Grid: (S/64, B*H). 256 thr = 4 waves.
// r12-verbatim (186us): sK/sV T2 XOR swizzle (stride 64, cs = c^((r&7)<<3));
// sP LDR=72 C-layout; ones-MFMA denominator; no mid-barrier; setprio;
// reversed qt order.
// ---------------------------------------------------------------------------
__global__ __launch_bounds__(256) void attn_kernel(
    short* __restrict__ QO, const short* __restrict__ Kt,
    const short* __restrict__ Vt) {
    constexpr int LDR = 64 + 8;           // sP stride
    __shared__ short sK[64 * 64];
    __shared__ short sV[64 * 64];
    __shared__ short sP[4][16 * LDR];

    const int tid = threadIdx.x;
    const int lane = tid & 63;
    const int wave = tid >> 6;
    const int quad = lane >> 4;
    const int l16 = lane & 15;
    const int qt = (int)gridDim.x - 1 - (int)blockIdx.x;
    const int bh = blockIdx.y;

    short* Qh = QO + (size_t)bh * SS * HD;
    const short* Kh = Kt + (size_t)bh * SS * HD;
    const short* Vh = Vt + (size_t)bh * HD * SS;

    const int qrow = qt * 64 + wave * 16 + l16;
    v8s qf[2];
    qf[0] = *(const v8s*)&Qh[(size_t)qrow * HD + quad * 8];
    qf[1] = *(const v8s*)&Qh[(size_t)qrow * HD + 32 + quad * 8];

    v8s onesb;
#pragma unroll
    for (int i = 0; i < 8; i++) onesb[i] = (short)0x3F80;  // bf16 1.0

    v4f o[4];
#pragma unroll
    for (int j = 0; j < 4; j++) o[j] = v4f_zero();
    v4f oSum = v4f_zero();
    float mOld[4];
#pragma unroll
    for (int r = 0; r < 4; r++) mOld[r] = NEG_BIG;

    const int qg_base = qt * 64 + wave * 16 + quad * 4;

    const int rc0 = (quad * 8) ^ ((l16 & 7) << 3);
    const int rc1 = (32 + quad * 8) ^ ((l16 & 7) << 3);

    for (int kt = 0; kt <= qt; kt++) {
        __syncthreads();
#pragma unroll
        for (int p = 0; p < 2; p++) {
            int idx = (p * 256 + tid) * 8;
            int r = idx >> 6;
            int c = idx & 63;
            int cs = c ^ ((r & 7) << 3);  // T2 XOR swizzle
            *(v8s*)&sK[r * 64 + cs] =
                *(const v8s*)&Kh[(size_t)(kt * 64 + r) * HD + c];
            *(v8s*)&sV[r * 64 + cs] =
                *(const v8s*)&Vh[(size_t)r * SS + kt * 64 + c];
        }
        __syncthreads();

        __builtin_amdgcn_s_setprio(1);
        v4f sc[4];
#pragma unroll
        for (int j = 0; j < 4; j++) {
            v8s b0 = *(const v8s*)&sK[(j * 16 + l16) * 64 + rc0];
            v8s b1 = *(const v8s*)&sK[(j * 16 + l16) * 64 + rc1];
            v4f t = __builtin_amdgcn_mfma_f32_16x16x32_bf16(qf[0], b0,
                                                            v4f_zero(), 0, 0, 0);
            sc[j] = __builtin_amdgcn_mfma_f32_16x16x32_bf16(qf[1], b1, t, 0, 0, 0);
        }
        __builtin_amdgcn_s_setprio(0);

        float x[4][4];
        const bool diag = (kt == qt);
#pragma unroll
        for (int j = 0; j < 4; j++) {
#pragma unroll
            for (int r = 0; r < 4; r++) {
                float v = sc[j][r] * 0.125f;
                if (diag) {
                    int kg = kt * 64 + j * 16 + l16;
                    int qg = qg_base + r;
                    if (kg > qg) v = NEG_BIG;
                }
                x[j][r] = v;
            }
        }

        float mNew[4], alpha[4];
#pragma unroll
        for (int r = 0; r < 4; r++) {
            float t = fmaxf(fmaxf(x[0][r], x[1][r]), fmaxf(x[2][r], x[3][r]));
#pragma unroll
            for (int off = 8; off >= 1; off >>= 1) t = fmaxf(t, __shfl_xor(t, off));
            mNew[r] = fmaxf(mOld[r], t);
            alpha[r] = __expf(mOld[r] - mNew[r]);
            mOld[r] = mNew[r];
        }

        short* Pw = sP[wave];
#pragma unroll
        for (int j = 0; j < 4; j++)
#pragma unroll
            for (int r = 0; r < 4; r++) {
                float p = __expf(x[j][r] - mNew[r]);
                Pw[(quad * 4 + r) * LDR + j * 16 + l16] = f2bf(p);
            }
#pragma unroll
        for (int j = 0; j < 4; j++)
#pragma unroll
            for (int r = 0; r < 4; r++) o[j][r] *= alpha[r];
#pragma unroll
        for (int r = 0; r < 4; r++) oSum[r] *= alpha[r];

        v8s pa0 = *(const v8s*)&Pw[l16 * LDR + quad * 8];
        v8s pa1 = *(const v8s*)&Pw[l16 * LDR + 32 + quad * 8];
        __builtin_amdgcn_s_setprio(1);
#pragma unroll
        for (int j = 0; j < 4; j++) {
            v8s v0 = *(const v8s*)&sV[(j * 16 + l16) * 64 + rc0];
            v8s v1 = *(const v8s*)&sV[(j * 16 + l16) * 64 + rc1];
            o[j] = __builtin_amdgcn_mfma_f32_16x16x32_bf16(pa0, v0, o[j], 0, 0, 0);
            o[j] = __builtin_amdgcn_mfma_f32_16x16x32_bf16(pa1, v1, o[j], 0, 0, 0);
        }
        oSum = __builtin_amdgcn_mfma_f32_16x16x32_bf16(pa0, onesb, oSum, 0, 0, 0);
        oSum = __builtin_amdgcn_mfma_f32_16x16x32_bf16(pa1, onesb, oSum, 0, 0, 0);
        __builtin_amdgcn_s_setprio(0);
    }

#pragma unroll
    for (int r = 0; r < 4; r++) {
        float inv = 1.f / oSum[r];
        int s = qg_base + r;
#pragma unroll
        for (int j = 0; j < 4; j++) {
            float v = o[j][r] * inv;
            Qh[(size_t)s * HD + j * 16 + l16] = f2bf(v);
        }
    }
}

// ---------------------------------------------------------------------------
extern "C" void kernel_launch(void* const* d_in, const int* in_sizes, int n_in,
                              void* d_out, int out_size, void* d_ws, size_t ws_size,
                              hipStream_t stream) {
    const float* query = (const float*)d_in[0];
    const float* key_ = (const float*)d_in[1];
    const float* value = (const float*)d_in[2];
    const float* Wq = (const float*)d_in[3];
    const float* bq = (const float*)d_in[4];
    const float* Wk = (const float*)d_in[5];
    const float* bk = (const float*)d_in[6];
    const float* Wv = (const float*)d_in[7];
    const float* bv = (const float*)d_in[8];
    const float* Wo = (const float*)d_in[9];
    const float* bo = (const float*)d_in[10];
    float* out = (float*)d_out;

    const size_t NE = (size_t)BB * SS * DD;   // 8388608
    const size_t WE = (size_t)DD * DD;        // 1048576 (one weight matrix)

    // Regions (shorts): DO0=d_out[0:NE], DO1=d_out[NE:2NE],
    //                   WS0=ws[0:NE],    WS1=ws[NE:2NE].
    short* qx  = (short*)d_out;            // DO0      [conv .. Qproj]
    short* kx  = (short*)d_out + NE;       // DO1      [conv .. Kproj]
    short* wqb = (short*)d_ws + NE;        // WS1[0:WE][conv .. Qproj] (pre-kw)
    short* wkb = (short*)d_out;            // DO0[0:WE][after Qproj .. Kproj]
    short* wvb = (short*)d_out + WE;       // DO0[WE:2WE][.. Vproj]
    short* vw  = (short*)d_out + NE;       // DO1      [Vproj .. attn] (kx dead)
    short* qw  = (short*)d_ws;             // WS0      [Qproj .. outproj]
    short* kw  = (short*)d_ws + NE;        // WS1      [Kproj .. attn]
    short* wob = (short*)d_ws + NE;        // WS1[0:WE][after attn .. outproj]

    dim3 blk(256);
    const int n8a = (int)(NE / 8);   // activation conv
    const int n8w = (int)(WE / 8);   // weight conv

    // 1) query,key -> bf16 (DO0, DO1); Wq -> bf16 (WS1, dead before kw)
    conv_bf16_kernel<<<dim3(2048), blk, 0, stream>>>(query, qx, n8a);
    conv_bf16_kernel<<<dim3(2048), blk, 0, stream>>>(key_, kx, n8a);
    conv_bf16_kernel<<<dim3(512), blk, 0, stream>>>(Wq, wqb, n8w);
    // 2) Q proj: reads DO0+WS1tail, writes WS0
    gemm_kernel<0><<<dim3(8, 64), blk, 0, stream>>>(qx, wqb, bq, qw);
    // 3) Wk -> DO0 (qx dead)
    conv_bf16_kernel<<<dim3(512), blk, 0, stream>>>(Wk, wkb, n8w);
    // 4) K proj: reads DO1+DO0head, writes WS1 (wqb dead)
    gemm_kernel<0><<<dim3(8, 64), blk, 0, stream>>>(kx, wkb, bk, kw);
    // 5) Wv -> DO0[WE:2WE]
    conv_bf16_kernel<<<dim3(512), blk, 0, stream>>>(Wv, wvb, n8w);
    // 6) V^T proj: reads DO0[WE:2WE] + value(fp32 input), writes DO1 (kx dead)
    gemm_kernel<1><<<dim3(64, 8), blk, 0, stream>>>(wvb, value, bv, vw);
    // 7) attention: reads WS0,WS1,DO1; O overwrites WS0
    attn_kernel<<<dim3(SS / 64, BB * HH), blk, 0, stream>>>(qw, kw, vw);
    // 8) Wo -> WS1 (kw dead)
    conv_bf16_kernel<<<dim3(512), blk, 0, stream>>>(Wo, wob, n8w);
    // 9) out proj: reads WS0 (O, remap) + WS1 (Wo), writes d_out fp32
    gemm_kernel<3><<<dim3(8, 64), blk, 0, stream>>>(qw, wob, bo, out);
}